// Round 1
// baseline (365.201 us; speedup 1.0000x reference)
//
#include <hip/hip_runtime.h>
#include <cstddef>
#include <cstdint>

#define BB    8
#define TT    2048
#define KIN   1024
#define NOUT  512
#define CHUNK 32
#define NCHUNK (TT / CHUNK)   // 64

// ---------------------------------------------------------------------------
// Kernel 1: f32 GEMM  C[m][n] = sum_k X[m][k] * W[n][k] + bias[n]
//   M = B*T = 16384, K = 1024, N = 512.  64x64 tile, 256 threads, 4x4/thread.
//   Writes directly into the "outputs" region of d_out.
// ---------------------------------------------------------------------------
__global__ __launch_bounds__(256) void gemm_f32_64x64(
    const float* __restrict__ X, const float* __restrict__ W,
    const float* __restrict__ bias, float* __restrict__ C) {
  __shared__ float As[16][65];   // [k][m], +1 pad
  __shared__ float Bs[16][65];   // [k][n], +1 pad

  const int m0  = blockIdx.y * 64;
  const int n0  = blockIdx.x * 64;
  const int tid = threadIdx.x;
  const int tx  = tid & 15;       // 0..15 -> n micro
  const int ty  = tid >> 4;       // 0..15 -> m micro
  const int lr  = tid >> 2;       // 0..63 load row
  const int lk  = (tid & 3) << 2; // 0,4,8,12 load k-base

  float acc[4][4] = {};

  const float* xa = X + (size_t)(m0 + lr) * KIN + lk;
  const float* wb = W + (size_t)(n0 + lr) * KIN + lk;

  for (int k0 = 0; k0 < KIN; k0 += 16) {
    float4 av = *reinterpret_cast<const float4*>(xa + k0);
    float4 bv = *reinterpret_cast<const float4*>(wb + k0);
    As[lk + 0][lr] = av.x; As[lk + 1][lr] = av.y;
    As[lk + 2][lr] = av.z; As[lk + 3][lr] = av.w;
    Bs[lk + 0][lr] = bv.x; Bs[lk + 1][lr] = bv.y;
    Bs[lk + 2][lr] = bv.z; Bs[lk + 3][lr] = bv.w;
    __syncthreads();
#pragma unroll
    for (int k = 0; k < 16; ++k) {
      float a[4], b[4];
#pragma unroll
      for (int i = 0; i < 4; ++i) a[i] = As[k][ty * 4 + i];
#pragma unroll
      for (int j = 0; j < 4; ++j) b[j] = Bs[k][tx * 4 + j];
#pragma unroll
      for (int i = 0; i < 4; ++i)
#pragma unroll
        for (int j = 0; j < 4; ++j) acc[i][j] += a[i] * b[j];
    }
    __syncthreads();
  }

  // epilogue: add bias, store float4 per row
  const int n = n0 + tx * 4;
  float4 bv = *reinterpret_cast<const float4*>(&bias[n]);
#pragma unroll
  for (int i = 0; i < 4; ++i) {
    const int m = m0 + ty * 4 + i;
    float4 r;
    r.x = acc[i][0] + bv.x;
    r.y = acc[i][1] + bv.y;
    r.z = acc[i][2] + bv.z;
    r.w = acc[i][3] + bv.w;
    *reinterpret_cast<float4*>(&C[(size_t)m * NOUT + n]) = r;
  }
}

// ---------------------------------------------------------------------------
// Kernel 2: local scan per (b, chunk) from zero init, in place over C.
//   v_k = d*v_{k-1} + (1-d)*c_k ; records chunk-final local state in vend.
//   grid = B*NCHUNK blocks, 512 threads (one per output feature).
// ---------------------------------------------------------------------------
__global__ __launch_bounds__(512) void scan_local(
    float* __restrict__ C, const float* __restrict__ decay,
    float* __restrict__ vend) {
  const int b = blockIdx.x / NCHUNK;
  const int c = blockIdx.x % NCHUNK;
  const int o = threadIdx.x;
  const float d   = decay[o];
  const float omd = 1.0f - d;
  float v = 0.0f;
  size_t base = ((size_t)b * TT + (size_t)c * CHUNK) * NOUT + o;
#pragma unroll 4
  for (int k = 0; k < CHUNK; ++k) {
    float x = C[base + (size_t)k * NOUT];
    v = d * v + omd * x;
    C[base + (size_t)k * NOUT] = v;
  }
  vend[((size_t)b * NCHUNK + c) * NOUT + o] = v;
}

// ---------------------------------------------------------------------------
// Kernel 3: chunk-level exclusive scan of carry states.
//   V_init[c] = d^CHUNK * V_init[c-1] + vend[c-1], V_init[0] = 0.
//   grid = B blocks, 512 threads.
// ---------------------------------------------------------------------------
__global__ __launch_bounds__(512) void scan_chunks(
    const float* __restrict__ vend, const float* __restrict__ decay,
    float* __restrict__ vinit) {
  const int b = blockIdx.x;
  const int o = threadIdx.x;
  const float d = decay[o];
  // d^32 via repeated squaring
  float d2 = d * d, d4 = d2 * d2, d8 = d4 * d4, d16 = d8 * d8;
  const float dL = d16 * d16;
  float V = 0.0f;
  for (int c = 0; c < NCHUNK; ++c) {
    const size_t idx = ((size_t)b * NCHUNK + c) * NOUT + o;
    vinit[idx] = V;
    V = dL * V + vend[idx];
  }
}

// ---------------------------------------------------------------------------
// Kernel 4: fixup  v_global = v_local + d^{k+1} * V_init  and mirror to states.
//   Also writes the states t=0 zero row.
// ---------------------------------------------------------------------------
__global__ __launch_bounds__(512) void scan_fixup(
    float* __restrict__ C, float* __restrict__ states,
    const float* __restrict__ decay, const float* __restrict__ vinit) {
  const int b = blockIdx.x / NCHUNK;
  const int c = blockIdx.x % NCHUNK;
  const int o = threadIdx.x;
  const float d = decay[o];
  const float V = vinit[((size_t)b * NCHUNK + c) * NOUT + o];
  float f = d;
  size_t obase = ((size_t)b * TT + (size_t)c * CHUNK) * NOUT + o;
  size_t sbase = ((size_t)b * (TT + 1) + (size_t)c * CHUNK + 1) * NOUT + o;
#pragma unroll 4
  for (int k = 0; k < CHUNK; ++k) {
    float val = C[obase + (size_t)k * NOUT] + f * V;
    C[obase + (size_t)k * NOUT]      = val;
    states[sbase + (size_t)k * NOUT] = val;
    f *= d;
  }
  if (c == 0) states[((size_t)b * (TT + 1)) * NOUT + o] = 0.0f;
}

// ---------------------------------------------------------------------------
// Fallback: fully sequential scan (only if ws_size is too small). Correct but
// slow; keeps the kernel robust to any workspace size.
// ---------------------------------------------------------------------------
__global__ __launch_bounds__(512) void scan_seq(
    float* __restrict__ C, float* __restrict__ states,
    const float* __restrict__ decay) {
  const int b = blockIdx.x;
  const int o = threadIdx.x;
  const float d   = decay[o];
  const float omd = 1.0f - d;
  float v = 0.0f;
  states[((size_t)b * (TT + 1)) * NOUT + o] = 0.0f;
  for (int t = 0; t < TT; ++t) {
    const size_t oi = ((size_t)b * TT + t) * NOUT + o;
    float x = C[oi];
    v = d * v + omd * x;
    C[oi] = v;
    states[((size_t)b * (TT + 1) + t + 1) * NOUT + o] = v;
  }
}

extern "C" void kernel_launch(void* const* d_in, const int* in_sizes, int n_in,
                              void* d_out, int out_size, void* d_ws, size_t ws_size,
                              hipStream_t stream) {
  const float* x     = (const float*)d_in[0];  // [B,T,IN]   f32
  const float* w     = (const float*)d_in[1];  // [OUT,IN]   f32
  const float* bias  = (const float*)d_in[2];  // [OUT]      f32
  const float* decay = (const float*)d_in[3];  // [OUT]      f32

  float* out    = (float*)d_out;                       // [B,T,OUT]
  float* states = out + (size_t)BB * TT * NOUT;        // [1,B,T+1,OUT]

  // 1) GEMM into the outputs region (holds `current` temporarily)
  dim3 gblk(256);
  dim3 ggrd(NOUT / 64, (BB * TT) / 64);   // (8, 256)
  gemm_f32_64x64<<<ggrd, gblk, 0, stream>>>(x, w, bias, out);

  // 2) parallel chunked scan (needs 2 MiB of workspace)
  const size_t need = (size_t)2 * BB * NCHUNK * NOUT * sizeof(float);
  if (ws_size >= need) {
    float* vend  = (float*)d_ws;
    float* vinit = vend + (size_t)BB * NCHUNK * NOUT;
    scan_local <<<BB * NCHUNK, NOUT, 0, stream>>>(out, decay, vend);
    scan_chunks<<<BB,          NOUT, 0, stream>>>(vend, decay, vinit);
    scan_fixup <<<BB * NCHUNK, NOUT, 0, stream>>>(out, states, decay, vinit);
  } else {
    scan_seq<<<BB, NOUT, 0, stream>>>(out, states, decay);
  }
}

// Round 2
// 116.958 us; speedup vs baseline: 3.1225x; 3.1225x over previous
//
#include <hip/hip_runtime.h>
#include <cstddef>
#include <cstdint>

#define BB    8
#define TT    2048
#define KIN   1024
#define NOUT  512
#define CHUNK 32
#define NCHUNK (TT / CHUNK)   // 64

#define BM 128
#define BN 128
#define BK 32

typedef __attribute__((ext_vector_type(8))) short     bf16x8;   // 8 bf16 = 4 VGPR
typedef __attribute__((ext_vector_type(8))) unsigned short u16x8;
typedef __attribute__((ext_vector_type(4))) float     f32x4;

// ---------------------------------------------------------------------------
// Split f32 -> (hi, lo) bf16 pair.  hi = rne(x), lo = rne(x - hi).
// Memory-bound; 8 floats per thread per iter, 16B vector stores.
// ---------------------------------------------------------------------------
__global__ __launch_bounds__(256) void split_bf16_kernel(
    const float* __restrict__ src, unsigned short* __restrict__ hi,
    unsigned short* __restrict__ lo, int n8) {
  int i = blockIdx.x * blockDim.x + threadIdx.x;
  const int stride = gridDim.x * blockDim.x;
  for (; i < n8; i += stride) {
    float4 x0 = reinterpret_cast<const float4*>(src)[2 * i];
    float4 x1 = reinterpret_cast<const float4*>(src)[2 * i + 1];
    float xs[8] = {x0.x, x0.y, x0.z, x0.w, x1.x, x1.y, x1.z, x1.w};
    u16x8 h, l;
#pragma unroll
    for (int j = 0; j < 8; ++j) {
      uint32_t b  = __float_as_uint(xs[j]);
      uint32_t r  = (b + 0x7fffu + ((b >> 16) & 1u)) >> 16;   // bf16 RNE
      h[j] = (unsigned short)r;
      float hf  = __uint_as_float(r << 16);
      float lof = xs[j] - hf;                                  // exact in f32
      uint32_t lb = __float_as_uint(lof);
      uint32_t r2 = (lb + 0x7fffu + ((lb >> 16) & 1u)) >> 16;
      l[j] = (unsigned short)r2;
    }
    reinterpret_cast<u16x8*>(hi)[i] = h;
    reinterpret_cast<u16x8*>(lo)[i] = l;
  }
}

// ---------------------------------------------------------------------------
// Split-bf16 MFMA GEMM (m97 structure: 128x128 tile, BK=32, 4 waves @ 64x64,
// linear LDS + global_load_lds(16B), 2-barrier K-loop).
// C[m][n] = sum_k X[m][k]*W[n][k] + bias[n], accumulating
// hi*hi + lo*hi + hi*lo in f32 via mfma_f32_16x16x32_bf16.
// ---------------------------------------------------------------------------
#define G2L(gp, sp)                                                        \
  __builtin_amdgcn_global_load_lds(                                       \
      (const __attribute__((address_space(1))) void*)(gp),                \
      (__attribute__((address_space(3))) void*)(sp), 16, 0, 0)

__global__ __launch_bounds__(256) void gemm_split_mfma(
    const unsigned short* __restrict__ Xhi, const unsigned short* __restrict__ Xlo,
    const unsigned short* __restrict__ Whi, const unsigned short* __restrict__ Wlo,
    const float* __restrict__ bias, float* __restrict__ C) {
  // linear LDS: Ahi | Alo | Bhi | Blo, each BM*BK bf16 (8KB) -> 32KB total
  __shared__ unsigned short sm[4 * BM * BK];
  unsigned short* sAhi = sm;
  unsigned short* sAlo = sm + 1 * BM * BK;
  unsigned short* sBhi = sm + 2 * BM * BK;
  unsigned short* sBlo = sm + 3 * BM * BK;

  const int tid  = threadIdx.x;
  const int wave = tid >> 6;
  const int lane = tid & 63;
  const int m0 = blockIdx.y * BM;
  const int n0 = blockIdx.x * BN;
  const int wm = (wave >> 1) * 64;   // wave's m-offset within tile (2x2 waves)
  const int wn = (wave & 1) * 64;    // wave's n-offset

  f32x4 acc[4][4] = {};              // 64 VGPR accumulator (4x4 of 16x16)

  // staging: thread tid covers LDS bytes tid*16 of a 64-row (4KB) chunk
  const int srow = tid >> 2;          // 0..63
  const int sk   = (tid & 3) << 3;    // 0,8,16,24
  const unsigned short* gAh = Xhi + (size_t)(m0 + srow) * KIN + sk;
  const unsigned short* gAl = Xlo + (size_t)(m0 + srow) * KIN + sk;
  const unsigned short* gBh = Whi + (size_t)(n0 + srow) * KIN + sk;
  const unsigned short* gBl = Wlo + (size_t)(n0 + srow) * KIN + sk;
  const size_t half = (size_t)64 * KIN;   // +64 rows in global

  const int ldsw = wave * 512;  // per-wave 512-element (1KB) slice of a chunk
  // fragment read offsets (elements)
  const int frow = lane & 15;
  const int fk   = (lane >> 4) << 3;

  for (int k0 = 0; k0 < KIN; k0 += BK) {
    __syncthreads();   // previous compute finished -> safe to overwrite LDS
    G2L(gAh + k0,        sAhi + ldsw);
    G2L(gAh + k0 + half, sAhi + 2048 + ldsw);
    G2L(gAl + k0,        sAlo + ldsw);
    G2L(gAl + k0 + half, sAlo + 2048 + ldsw);
    G2L(gBh + k0,        sBhi + ldsw);
    G2L(gBh + k0 + half, sBhi + 2048 + ldsw);
    G2L(gBl + k0,        sBlo + ldsw);
    G2L(gBl + k0 + half, sBlo + 2048 + ldsw);
    __syncthreads();   // compiler drains vmcnt before barrier -> LDS ready

    bf16x8 ah[4], al[4];
#pragma unroll
    for (int mi = 0; mi < 4; ++mi) {
      const int off = (wm + mi * 16 + frow) * BK + fk;
      ah[mi] = *reinterpret_cast<const bf16x8*>(sAhi + off);
      al[mi] = *reinterpret_cast<const bf16x8*>(sAlo + off);
    }
#pragma unroll
    for (int ni = 0; ni < 4; ++ni) {
      const int off = (wn + ni * 16 + frow) * BK + fk;
      bf16x8 bh = *reinterpret_cast<const bf16x8*>(sBhi + off);
      bf16x8 bl = *reinterpret_cast<const bf16x8*>(sBlo + off);
#pragma unroll
      for (int mi = 0; mi < 4; ++mi) {
        acc[mi][ni] = __builtin_amdgcn_mfma_f32_16x16x32_bf16(ah[mi], bh, acc[mi][ni], 0, 0, 0);
        acc[mi][ni] = __builtin_amdgcn_mfma_f32_16x16x32_bf16(al[mi], bh, acc[mi][ni], 0, 0, 0);
        acc[mi][ni] = __builtin_amdgcn_mfma_f32_16x16x32_bf16(ah[mi], bl, acc[mi][ni], 0, 0, 0);
      }
    }
  }

  // epilogue: C/D layout col = lane&15, row = (lane>>4)*4 + r  [m89-verified]
  const int colb  = n0 + wn + (lane & 15);
  const int rowb  = m0 + wm + ((lane >> 4) << 2);
#pragma unroll
  for (int ni = 0; ni < 4; ++ni) {
    const float bv = bias[colb + ni * 16];
#pragma unroll
    for (int mi = 0; mi < 4; ++mi) {
#pragma unroll
      for (int r = 0; r < 4; ++r) {
        C[(size_t)(rowb + mi * 16 + r) * NOUT + colb + ni * 16] = acc[mi][ni][r] + bv;
      }
    }
  }
}

// ---------------------------------------------------------------------------
// Fallback f32 GEMM (round-1, verified) — used only if workspace is too small.
// ---------------------------------------------------------------------------
__global__ __launch_bounds__(256) void gemm_f32_64x64(
    const float* __restrict__ X, const float* __restrict__ W,
    const float* __restrict__ bias, float* __restrict__ C) {
  __shared__ float As[16][65];
  __shared__ float Bs[16][65];
  const int m0  = blockIdx.y * 64;
  const int n0  = blockIdx.x * 64;
  const int tid = threadIdx.x;
  const int tx  = tid & 15;
  const int ty  = tid >> 4;
  const int lr  = tid >> 2;
  const int lk  = (tid & 3) << 2;
  float acc[4][4] = {};
  const float* xa = X + (size_t)(m0 + lr) * KIN + lk;
  const float* wb = W + (size_t)(n0 + lr) * KIN + lk;
  for (int k0 = 0; k0 < KIN; k0 += 16) {
    float4 av = *reinterpret_cast<const float4*>(xa + k0);
    float4 bv = *reinterpret_cast<const float4*>(wb + k0);
    As[lk + 0][lr] = av.x; As[lk + 1][lr] = av.y;
    As[lk + 2][lr] = av.z; As[lk + 3][lr] = av.w;
    Bs[lk + 0][lr] = bv.x; Bs[lk + 1][lr] = bv.y;
    Bs[lk + 2][lr] = bv.z; Bs[lk + 3][lr] = bv.w;
    __syncthreads();
#pragma unroll
    for (int k = 0; k < 16; ++k) {
      float a[4], b[4];
#pragma unroll
      for (int i = 0; i < 4; ++i) a[i] = As[k][ty * 4 + i];
#pragma unroll
      for (int j = 0; j < 4; ++j) b[j] = Bs[k][tx * 4 + j];
#pragma unroll
      for (int i = 0; i < 4; ++i)
#pragma unroll
        for (int j = 0; j < 4; ++j) acc[i][j] += a[i] * b[j];
    }
    __syncthreads();
  }
  const int n = n0 + tx * 4;
  float4 bv = *reinterpret_cast<const float4*>(&bias[n]);
#pragma unroll
  for (int i = 0; i < 4; ++i) {
    const int m = m0 + ty * 4 + i;
    float4 r;
    r.x = acc[i][0] + bv.x; r.y = acc[i][1] + bv.y;
    r.z = acc[i][2] + bv.z; r.w = acc[i][3] + bv.w;
    *reinterpret_cast<float4*>(&C[(size_t)m * NOUT + n]) = r;
  }
}

// ---------------------------------------------------------------------------
// Chunked parallel scan (unchanged from round 1, verified).
// ---------------------------------------------------------------------------
__global__ __launch_bounds__(512) void scan_local(
    float* __restrict__ C, const float* __restrict__ decay,
    float* __restrict__ vend) {
  const int b = blockIdx.x / NCHUNK;
  const int c = blockIdx.x % NCHUNK;
  const int o = threadIdx.x;
  const float d   = decay[o];
  const float omd = 1.0f - d;
  float v = 0.0f;
  size_t base = ((size_t)b * TT + (size_t)c * CHUNK) * NOUT + o;
#pragma unroll 4
  for (int k = 0; k < CHUNK; ++k) {
    float x = C[base + (size_t)k * NOUT];
    v = d * v + omd * x;
    C[base + (size_t)k * NOUT] = v;
  }
  vend[((size_t)b * NCHUNK + c) * NOUT + o] = v;
}

__global__ __launch_bounds__(512) void scan_chunks(
    const float* __restrict__ vend, const float* __restrict__ decay,
    float* __restrict__ vinit) {
  const int b = blockIdx.x;
  const int o = threadIdx.x;
  const float d = decay[o];
  float d2 = d * d, d4 = d2 * d2, d8 = d4 * d4, d16 = d8 * d8;
  const float dL = d16 * d16;   // d^CHUNK
  float V = 0.0f;
  for (int c = 0; c < NCHUNK; ++c) {
    const size_t idx = ((size_t)b * NCHUNK + c) * NOUT + o;
    vinit[idx] = V;
    V = dL * V + vend[idx];
  }
}

__global__ __launch_bounds__(512) void scan_fixup(
    float* __restrict__ C, float* __restrict__ states,
    const float* __restrict__ decay, const float* __restrict__ vinit) {
  const int b = blockIdx.x / NCHUNK;
  const int c = blockIdx.x % NCHUNK;
  const int o = threadIdx.x;
  const float d = decay[o];
  const float V = vinit[((size_t)b * NCHUNK + c) * NOUT + o];
  float f = d;
  size_t obase = ((size_t)b * TT + (size_t)c * CHUNK) * NOUT + o;
  size_t sbase = ((size_t)b * (TT + 1) + (size_t)c * CHUNK + 1) * NOUT + o;
#pragma unroll 4
  for (int k = 0; k < CHUNK; ++k) {
    float val = C[obase + (size_t)k * NOUT] + f * V;
    C[obase + (size_t)k * NOUT]      = val;
    states[sbase + (size_t)k * NOUT] = val;
    f *= d;
  }
  if (c == 0) states[((size_t)b * (TT + 1)) * NOUT + o] = 0.0f;
}

__global__ __launch_bounds__(512) void scan_seq(
    float* __restrict__ C, float* __restrict__ states,
    const float* __restrict__ decay) {
  const int b = blockIdx.x;
  const int o = threadIdx.x;
  const float d   = decay[o];
  const float omd = 1.0f - d;
  float v = 0.0f;
  states[((size_t)b * (TT + 1)) * NOUT + o] = 0.0f;
  for (int t = 0; t < TT; ++t) {
    const size_t oi = ((size_t)b * TT + t) * NOUT + o;
    float x = C[oi];
    v = d * v + omd * x;
    C[oi] = v;
    states[((size_t)b * (TT + 1) + t + 1) * NOUT + o] = v;
  }
}

extern "C" void kernel_launch(void* const* d_in, const int* in_sizes, int n_in,
                              void* d_out, int out_size, void* d_ws, size_t ws_size,
                              hipStream_t stream) {
  const float* x     = (const float*)d_in[0];  // [B,T,IN]
  const float* w     = (const float*)d_in[1];  // [OUT,IN]
  const float* bias  = (const float*)d_in[2];  // [OUT]
  const float* decay = (const float*)d_in[3];  // [OUT]

  float* out    = (float*)d_out;                 // [B,T,OUT]
  float* states = out + (size_t)BB * TT * NOUT;  // [1,B,T+1,OUT]

  const size_t szX = (size_t)BB * TT * KIN;      // 16.78M elems
  const size_t szW = (size_t)NOUT * KIN;         // 0.52M elems
  const size_t scan_elems = (size_t)BB * NCHUNK * NOUT;
  const size_t need_mfma = (2 * szX + 2 * szW) * sizeof(unsigned short)
                         + 2 * scan_elems * sizeof(float);      // ~71.3 MB
  const size_t need_scan = 2 * scan_elems * sizeof(float);      // 2 MB

  if (ws_size >= need_mfma) {
    unsigned short* Xhi = (unsigned short*)d_ws;
    unsigned short* Xlo = Xhi + szX;
    unsigned short* Whi = Xlo + szX;
    unsigned short* Wlo = Whi + szW;
    float* vend  = (float*)(Wlo + szW);
    float* vinit = vend + scan_elems;

    split_bf16_kernel<<<2048, 256, 0, stream>>>(x, Xhi, Xlo, (int)(szX / 8));
    split_bf16_kernel<<<256,  256, 0, stream>>>(w, Whi, Wlo, (int)(szW / 8));
    gemm_split_mfma<<<dim3(NOUT / BN, (BB * TT) / BM), 256, 0, stream>>>(
        Xhi, Xlo, Whi, Wlo, bias, out);
    scan_local <<<BB * NCHUNK, NOUT, 0, stream>>>(out, decay, vend);
    scan_chunks<<<BB,          NOUT, 0, stream>>>(vend, decay, vinit);
    scan_fixup <<<BB * NCHUNK, NOUT, 0, stream>>>(out, states, decay, vinit);
  } else if (ws_size >= need_scan) {
    float* vend  = (float*)d_ws;
    float* vinit = vend + scan_elems;
    gemm_f32_64x64<<<dim3(NOUT / 64, (BB * TT) / 64), 256, 0, stream>>>(x, w, bias, out);
    scan_local <<<BB * NCHUNK, NOUT, 0, stream>>>(out, decay, vend);
    scan_chunks<<<BB,          NOUT, 0, stream>>>(vend, decay, vinit);
    scan_fixup <<<BB * NCHUNK, NOUT, 0, stream>>>(out, states, decay, vinit);
  } else {
    gemm_f32_64x64<<<dim3(NOUT / 64, (BB * TT) / 64), 256, 0, stream>>>(x, w, bias, out);
    scan_seq<<<BB, NOUT, 0, stream>>>(out, states, decay);
  }
}

// Round 3
// 93.490 us; speedup vs baseline: 3.9063x; 1.2510x over previous
//
#include <hip/hip_runtime.h>
#include <hip/hip_bf16.h>
#include <cstddef>
#include <cstdint>

#define BB    8
#define TT    2048
#define KIN   1024
#define NOUT  512
#define CHUNK 32
#define NCHUNK (TT / CHUNK)   // 64

#define BM 128
#define BN 128
#define BK 32
#define NKSTEP (KIN / BK)     // 32

typedef __attribute__((ext_vector_type(8))) short          bf16x8;
typedef __attribute__((ext_vector_type(8))) unsigned short u16x8;
typedef __attribute__((ext_vector_type(4))) float          f32x4;

// ---------------------------------------------------------------------------
// Split f32 -> (hi, lo) bf16 pair (W only; X split is fused into the GEMM).
// ---------------------------------------------------------------------------
__global__ __launch_bounds__(256) void split_bf16_kernel(
    const float* __restrict__ src, unsigned short* __restrict__ hi,
    unsigned short* __restrict__ lo, int n8) {
  int i = blockIdx.x * blockDim.x + threadIdx.x;
  const int stride = gridDim.x * blockDim.x;
  for (; i < n8; i += stride) {
    float4 x0 = reinterpret_cast<const float4*>(src)[2 * i];
    float4 x1 = reinterpret_cast<const float4*>(src)[2 * i + 1];
    float xs[8] = {x0.x, x0.y, x0.z, x0.w, x1.x, x1.y, x1.z, x1.w};
    u16x8 h, l;
#pragma unroll
    for (int j = 0; j < 8; ++j) {
      uint32_t b  = __float_as_uint(xs[j]);
      uint32_t r  = (b + 0x7fffu + ((b >> 16) & 1u)) >> 16;   // bf16 RNE
      h[j] = (unsigned short)r;
      float hf  = __uint_as_float(r << 16);
      float lof = xs[j] - hf;
      uint32_t lb = __float_as_uint(lof);
      uint32_t r2 = (lb + 0x7fffu + ((lb >> 16) & 1u)) >> 16;
      l[j] = (unsigned short)r2;
    }
    reinterpret_cast<u16x8*>(hi)[i] = h;
    reinterpret_cast<u16x8*>(lo)[i] = l;
  }
}

#define G2L(gp, sp)                                                        \
  __builtin_amdgcn_global_load_lds(                                       \
      (const __attribute__((address_space(1))) void*)(gp),                \
      (__attribute__((address_space(3))) void*)(sp), 16, 0, 0)

// ---------------------------------------------------------------------------
// Fused GEMM: A = f32 X staged directly (split to bf16 hi/lo in registers),
// B = pre-split W hi/lo.  128x128 tile, BK=32, dbuf LDS (64KB), single
// barrier per K-step, XOR-swizzled LDS (pre-swizzled global source, rule #21).
//   C = Xhi*Whi + Xlo*Whi + Xhi*Wlo + bias
// grid = (128 m-tiles, 4 n-tiles): all 4 n-blocks of an m-tile share an XCD.
// ---------------------------------------------------------------------------
__global__ __launch_bounds__(256) void gemm_fused(
    const float* __restrict__ X, const unsigned short* __restrict__ Whi,
    const unsigned short* __restrict__ Wlo, const float* __restrict__ bias,
    float* __restrict__ C) {
  // per buffer: A f32 16KB | Bhi 8KB | Blo 8KB = 32KB; x2 buffers = 64KB
  __shared__ __align__(16) unsigned char smem[2 * 32768];

  const int tid  = threadIdx.x;
  const int wave = tid >> 6;
  const int lane = tid & 63;
  const int m0 = blockIdx.x * BM;
  const int n0 = blockIdx.y * BN;
  const int wm = (wave >> 1) * 64;
  const int wn = (wave & 1) * 64;
  const int frow = lane & 15;

  // --- staging constants (inverse-swizzled global source, linear LDS dest) ---
  // A: row slot (16B = 4 f32) index swizzle  s_lds = s_g ^ (row & 7)
  const int sgA  = (lane & 7) ^ (lane >> 3);
  const int arow = wave * 8 + (lane >> 3);
  // B: row slot (16B = 8 bf16) swizzle  s_lds = s_g ^ ((row>>1) & 3)
  const int sgB  = (lane & 3) ^ ((lane >> 3) & 3);
  const int brow = wave * 16 + (lane >> 2);

  const float*          gA  = X   + (size_t)(m0 + arow) * KIN + sgA * 4;
  const unsigned short* gBh = Whi + (size_t)(n0 + brow) * KIN + sgB * 8;
  const unsigned short* gBl = Wlo + (size_t)(n0 + brow) * KIN + sgB * 8;
  const int ldsw = wave * 1024;   // bytes: wave's lane-linear slice per issue

  // --- fragment-read constants (swizzled byte offsets, constant per lane) ---
  const int s0  = (lane >> 4) * 2;                    // f32 16B-slot of fk
  const int oA0 = ((s0)     ^ (lane & 7)) << 4;
  const int oA1 = ((s0 + 1) ^ (lane & 7)) << 4;
  const int oB  = ((lane >> 4) ^ ((lane >> 1) & 3)) << 4;

  f32x4 acc[4][4] = {};

  auto stage = [&](int p, int k0) {
    unsigned char* b = smem + p * 32768;
#pragma unroll
    for (int i = 0; i < 4; ++i)
      G2L(gA + (size_t)i * 32 * KIN + k0, b + i * 4096 + ldsw);
#pragma unroll
    for (int i = 0; i < 2; ++i) {
      G2L(gBh + (size_t)i * 64 * KIN + k0, b + 16384 + i * 4096 + ldsw);
      G2L(gBl + (size_t)i * 64 * KIN + k0, b + 24576 + i * 4096 + ldsw);
    }
  };

  stage(0, 0);
  for (int t = 0; t < NKSTEP; ++t) {
    __syncthreads();   // implicit vmcnt(0) drain: stage(t) landed; prev compute done
    if (t + 1 < NKSTEP) stage((t + 1) & 1, (t + 1) * BK);  // flies under compute

    const unsigned char* cb = smem + (t & 1) * 32768;

    // A fragments: read f32, split to hi/lo bf16 in registers
    bf16x8 ah[4], al[4];
#pragma unroll
    for (int mi = 0; mi < 4; ++mi) {
      const unsigned char* ap = cb + (size_t)(wm + mi * 16 + frow) * 128;
      float4 x0 = *reinterpret_cast<const float4*>(ap + oA0);
      float4 x1 = *reinterpret_cast<const float4*>(ap + oA1);
      float xs[8] = {x0.x, x0.y, x0.z, x0.w, x1.x, x1.y, x1.z, x1.w};
#pragma unroll
      for (int j = 0; j < 8; ++j) {
        __hip_bfloat16 hb = __float2bfloat16(xs[j]);
        unsigned short hu; __builtin_memcpy(&hu, &hb, 2);
        float hf = __uint_as_float((uint32_t)hu << 16);
        __hip_bfloat16 lb = __float2bfloat16(xs[j] - hf);
        unsigned short lu; __builtin_memcpy(&lu, &lb, 2);
        ah[mi][j] = (short)hu;
        al[mi][j] = (short)lu;
      }
    }

#pragma unroll
    for (int ni = 0; ni < 4; ++ni) {
      const unsigned char* bp = cb + 16384 + (size_t)(wn + ni * 16 + frow) * 64 + oB;
      bf16x8 bh = *reinterpret_cast<const bf16x8*>(bp);
      bf16x8 bl = *reinterpret_cast<const bf16x8*>(bp + 8192);
#pragma unroll
      for (int mi = 0; mi < 4; ++mi) {
        acc[mi][ni] = __builtin_amdgcn_mfma_f32_16x16x32_bf16(ah[mi], bh, acc[mi][ni], 0, 0, 0);
        acc[mi][ni] = __builtin_amdgcn_mfma_f32_16x16x32_bf16(al[mi], bh, acc[mi][ni], 0, 0, 0);
        acc[mi][ni] = __builtin_amdgcn_mfma_f32_16x16x32_bf16(ah[mi], bl, acc[mi][ni], 0, 0, 0);
      }
    }
  }

  // epilogue: C/D layout col = lane&15, row = (lane>>4)*4 + r  [m89-verified]
  const int colb = n0 + wn + (lane & 15);
  const int rowb = m0 + wm + ((lane >> 4) << 2);
#pragma unroll
  for (int ni = 0; ni < 4; ++ni) {
    const float bv = bias[colb + ni * 16];
#pragma unroll
    for (int mi = 0; mi < 4; ++mi) {
#pragma unroll
      for (int r = 0; r < 4; ++r) {
        C[(size_t)(rowb + mi * 16 + r) * NOUT + colb + ni * 16] = acc[mi][ni][r] + bv;
      }
    }
  }
}

// ---------------------------------------------------------------------------
// Fallback f32 GEMM (verified R1) — only if workspace is too small.
// ---------------------------------------------------------------------------
__global__ __launch_bounds__(256) void gemm_f32_64x64(
    const float* __restrict__ X, const float* __restrict__ W,
    const float* __restrict__ bias, float* __restrict__ C) {
  __shared__ float As[16][65];
  __shared__ float Bs[16][65];
  const int m0  = blockIdx.y * 64;
  const int n0  = blockIdx.x * 64;
  const int tid = threadIdx.x;
  const int tx  = tid & 15;
  const int ty  = tid >> 4;
  const int lr  = tid >> 2;
  const int lk  = (tid & 3) << 2;
  float acc[4][4] = {};
  const float* xa = X + (size_t)(m0 + lr) * KIN + lk;
  const float* wb = W + (size_t)(n0 + lr) * KIN + lk;
  for (int k0 = 0; k0 < KIN; k0 += 16) {
    float4 av = *reinterpret_cast<const float4*>(xa + k0);
    float4 bv = *reinterpret_cast<const float4*>(wb + k0);
    As[lk + 0][lr] = av.x; As[lk + 1][lr] = av.y;
    As[lk + 2][lr] = av.z; As[lk + 3][lr] = av.w;
    Bs[lk + 0][lr] = bv.x; Bs[lk + 1][lr] = bv.y;
    Bs[lk + 2][lr] = bv.z; Bs[lk + 3][lr] = bv.w;
    __syncthreads();
#pragma unroll
    for (int k = 0; k < 16; ++k) {
      float a[4], b[4];
#pragma unroll
      for (int i = 0; i < 4; ++i) a[i] = As[k][ty * 4 + i];
#pragma unroll
      for (int j = 0; j < 4; ++j) b[j] = Bs[k][tx * 4 + j];
#pragma unroll
      for (int i = 0; i < 4; ++i)
#pragma unroll
        for (int j = 0; j < 4; ++j) acc[i][j] += a[i] * b[j];
    }
    __syncthreads();
  }
  const int n = n0 + tx * 4;
  float4 bv = *reinterpret_cast<const float4*>(&bias[n]);
#pragma unroll
  for (int i = 0; i < 4; ++i) {
    const int m = m0 + ty * 4 + i;
    float4 r;
    r.x = acc[i][0] + bv.x; r.y = acc[i][1] + bv.y;
    r.z = acc[i][2] + bv.z; r.w = acc[i][3] + bv.w;
    *reinterpret_cast<float4*>(&C[(size_t)m * NOUT + n]) = r;
  }
}

// ---------------------------------------------------------------------------
// Scan, 2 passes over C:
//   pass 1: read-only local scan -> vend      (no C write)
//   pass 2 (chunks): compose carries
//   pass 3 (fixup): recompute local scan seeded with v = V_init, write out+states
// ---------------------------------------------------------------------------
__global__ __launch_bounds__(512) void scan_vend(
    const float* __restrict__ C, const float* __restrict__ decay,
    float* __restrict__ vend) {
  const int b = blockIdx.x / NCHUNK;
  const int c = blockIdx.x % NCHUNK;
  const int o = threadIdx.x;
  const float d   = decay[o];
  const float omd = 1.0f - d;
  float v = 0.0f;
  size_t base = ((size_t)b * TT + (size_t)c * CHUNK) * NOUT + o;
#pragma unroll 4
  for (int k = 0; k < CHUNK; ++k) {
    v = d * v + omd * C[base + (size_t)k * NOUT];
  }
  vend[((size_t)b * NCHUNK + c) * NOUT + o] = v;
}

__global__ __launch_bounds__(512) void scan_chunks(
    const float* __restrict__ vend, const float* __restrict__ decay,
    float* __restrict__ vinit) {
  const int b = blockIdx.x;
  const int o = threadIdx.x;
  const float d = decay[o];
  float d2 = d * d, d4 = d2 * d2, d8 = d4 * d4, d16 = d8 * d8;
  const float dL = d16 * d16;   // d^CHUNK
  float V = 0.0f;
  for (int c = 0; c < NCHUNK; ++c) {
    const size_t idx = ((size_t)b * NCHUNK + c) * NOUT + o;
    vinit[idx] = V;
    V = dL * V + vend[idx];
  }
}

__global__ __launch_bounds__(512) void scan_fixup(
    float* __restrict__ C, float* __restrict__ states,
    const float* __restrict__ decay, const float* __restrict__ vinit) {
  const int b = blockIdx.x / NCHUNK;
  const int c = blockIdx.x % NCHUNK;
  const int o = threadIdx.x;
  const float d   = decay[o];
  const float omd = 1.0f - d;
  float v = vinit[((size_t)b * NCHUNK + c) * NOUT + o];  // seed = carry-in
  size_t obase = ((size_t)b * TT + (size_t)c * CHUNK) * NOUT + o;
  size_t sbase = ((size_t)b * (TT + 1) + (size_t)c * CHUNK + 1) * NOUT + o;
#pragma unroll 4
  for (int k = 0; k < CHUNK; ++k) {
    v = d * v + omd * C[obase + (size_t)k * NOUT];
    C[obase + (size_t)k * NOUT]      = v;
    states[sbase + (size_t)k * NOUT] = v;
  }
  if (c == 0) states[((size_t)b * (TT + 1)) * NOUT + o] = 0.0f;
}

__global__ __launch_bounds__(512) void scan_seq(
    float* __restrict__ C, float* __restrict__ states,
    const float* __restrict__ decay) {
  const int b = blockIdx.x;
  const int o = threadIdx.x;
  const float d   = decay[o];
  const float omd = 1.0f - d;
  float v = 0.0f;
  states[((size_t)b * (TT + 1)) * NOUT + o] = 0.0f;
  for (int t = 0; t < TT; ++t) {
    const size_t oi = ((size_t)b * TT + t) * NOUT + o;
    float x = C[oi];
    v = d * v + omd * x;
    C[oi] = v;
    states[((size_t)b * (TT + 1) + t + 1) * NOUT + o] = v;
  }
}

extern "C" void kernel_launch(void* const* d_in, const int* in_sizes, int n_in,
                              void* d_out, int out_size, void* d_ws, size_t ws_size,
                              hipStream_t stream) {
  const float* x     = (const float*)d_in[0];  // [B,T,IN]
  const float* w     = (const float*)d_in[1];  // [OUT,IN]
  const float* bias  = (const float*)d_in[2];  // [OUT]
  const float* decay = (const float*)d_in[3];  // [OUT]

  float* out    = (float*)d_out;                 // [B,T,OUT]
  float* states = out + (size_t)BB * TT * NOUT;  // [1,B,T+1,OUT]

  const size_t szW = (size_t)NOUT * KIN;                      // 0.52M elems
  const size_t scan_elems = (size_t)BB * NCHUNK * NOUT;
  const size_t need = 2 * szW * sizeof(unsigned short)
                    + 2 * scan_elems * sizeof(float);         // ~4 MB

  if (ws_size >= need) {
    unsigned short* Whi = (unsigned short*)d_ws;
    unsigned short* Wlo = Whi + szW;
    float* vend  = (float*)(Wlo + szW);
    float* vinit = vend + scan_elems;

    split_bf16_kernel<<<256, 256, 0, stream>>>(w, Whi, Wlo, (int)(szW / 8));
    gemm_fused<<<dim3((BB * TT) / BM, NOUT / BN), 256, 0, stream>>>(
        x, Whi, Wlo, bias, out);
    scan_vend  <<<BB * NCHUNK, NOUT, 0, stream>>>(out, decay, vend);
    scan_chunks<<<BB,          NOUT, 0, stream>>>(vend, decay, vinit);
    scan_fixup <<<BB * NCHUNK, NOUT, 0, stream>>>(out, states, decay, vinit);
  } else {
    gemm_f32_64x64<<<dim3(NOUT / 64, (BB * TT) / 64), 256, 0, stream>>>(x, w, bias, out);
    scan_seq<<<BB, NOUT, 0, stream>>>(out, states, decay);
  }
}

// Round 4
// 92.712 us; speedup vs baseline: 3.9391x; 1.0084x over previous
//
#include <hip/hip_runtime.h>
#include <hip/hip_bf16.h>
#include <cstddef>
#include <cstdint>

#define BB    8
#define TT    2048
#define KIN   1024
#define NOUT  512
#define CHUNK 32
#define NCHUNK (TT / CHUNK)   // 64

#define BM 128
#define BN 128
#define BK 32
#define NKSTEP (KIN / BK)     // 32

typedef __attribute__((ext_vector_type(8))) short          bf16x8;
typedef __attribute__((ext_vector_type(8))) unsigned short u16x8;
typedef __attribute__((ext_vector_type(4))) float          f32x4;
typedef __attribute__((ext_vector_type(4))) unsigned int   u32x4;

// ---------------------------------------------------------------------------
// Split f32 -> (hi, lo) bf16 pair with RNE (W only; X split fused into GEMM).
// ---------------------------------------------------------------------------
__global__ __launch_bounds__(256) void split_bf16_kernel(
    const float* __restrict__ src, unsigned short* __restrict__ hi,
    unsigned short* __restrict__ lo, int n8) {
  int i = blockIdx.x * blockDim.x + threadIdx.x;
  const int stride = gridDim.x * blockDim.x;
  for (; i < n8; i += stride) {
    float4 x0 = reinterpret_cast<const float4*>(src)[2 * i];
    float4 x1 = reinterpret_cast<const float4*>(src)[2 * i + 1];
    float xs[8] = {x0.x, x0.y, x0.z, x0.w, x1.x, x1.y, x1.z, x1.w};
    u16x8 h, l;
#pragma unroll
    for (int j = 0; j < 8; ++j) {
      uint32_t b  = __float_as_uint(xs[j]);
      uint32_t r  = (b + 0x7fffu + ((b >> 16) & 1u)) >> 16;   // bf16 RNE
      h[j] = (unsigned short)r;
      float hf  = __uint_as_float(r << 16);
      float lof = xs[j] - hf;
      uint32_t lb = __float_as_uint(lof);
      uint32_t r2 = (lb + 0x7fffu + ((lb >> 16) & 1u)) >> 16;
      l[j] = (unsigned short)r2;
    }
    reinterpret_cast<u16x8*>(hi)[i] = h;
    reinterpret_cast<u16x8*>(lo)[i] = l;
  }
}

#define G2L(gp, sp)                                                        \
  __builtin_amdgcn_global_load_lds(                                       \
      (const __attribute__((address_space(1))) void*)(gp),                \
      (__attribute__((address_space(3))) void*)(sp), 16, 0, 0)

// ---------------------------------------------------------------------------
// Fused GEMM: A = f32 X staged directly (trunc-Dekker split to bf16 hi/lo in
// registers: hi=trunc16(x) via v_perm, lo=x-hf exact, trunc to bf16).
// B = pre-split W hi/lo.  128x128 tile, BK=32, SINGLE 32KB LDS buffer,
// m97 2-barrier K-loop, XOR-swizzled LDS (pre-swizzled global source).
//   C = Xhi*Whi + Xlo*Whi + Xhi*Wlo + bias
// grid = (128 m-tiles, 4 n-tiles): 128%8==0 -> all 4 n-blocks of an m-tile
// land on the same XCD (verified R3: FETCH 133->41MB).
// ---------------------------------------------------------------------------
__global__ __launch_bounds__(256, 2) void gemm_fused(
    const float* __restrict__ X, const unsigned short* __restrict__ Whi,
    const unsigned short* __restrict__ Wlo, const float* __restrict__ bias,
    float* __restrict__ C) {
  // A f32 16KB | Bhi 8KB | Blo 8KB = 32KB (single buffer)
  __shared__ __align__(16) unsigned char smem[32768];

  const int tid  = threadIdx.x;
  const int wave = tid >> 6;
  const int lane = tid & 63;
  const int m0 = blockIdx.x * BM;
  const int n0 = blockIdx.y * BN;
  const int wm = (wave >> 1) * 64;
  const int wn = (wave & 1) * 64;
  const int frow = lane & 15;

  // --- staging constants (inverse-swizzled global source, linear LDS dest) ---
  const int sgA  = (lane & 7) ^ (lane >> 3);        // A: slot ^= row&7 (16B slots)
  const int arow = wave * 8 + (lane >> 3);
  const int sgB  = (lane & 3) ^ ((lane >> 3) & 3);  // B: slot ^= (row>>1)&3
  const int brow = wave * 16 + (lane >> 2);

  const float*          gA  = X   + (size_t)(m0 + arow) * KIN + sgA * 4;
  const unsigned short* gBh = Whi + (size_t)(n0 + brow) * KIN + sgB * 8;
  const unsigned short* gBl = Wlo + (size_t)(n0 + brow) * KIN + sgB * 8;
  const int ldsw = wave * 1024;   // bytes: wave's lane-linear slice per issue

  // --- fragment-read constants (swizzled byte offsets, constant per lane) ---
  const int s0  = (lane >> 4) * 2;
  const int oA0 = ((s0)     ^ (lane & 7)) << 4;
  const int oA1 = ((s0 + 1) ^ (lane & 7)) << 4;
  const int oB  = ((lane >> 4) ^ ((lane >> 1) & 3)) << 4;

  f32x4 acc[4][4] = {};

  auto stage = [&](int k0) {
#pragma unroll
    for (int i = 0; i < 4; ++i)
      G2L(gA + (size_t)i * 32 * KIN + k0, smem + i * 4096 + ldsw);
#pragma unroll
    for (int i = 0; i < 2; ++i) {
      G2L(gBh + (size_t)i * 64 * KIN + k0, smem + 16384 + i * 4096 + ldsw);
      G2L(gBl + (size_t)i * 64 * KIN + k0, smem + 24576 + i * 4096 + ldsw);
    }
  };

  for (int t = 0; t < NKSTEP; ++t) {
    __syncthreads();            // previous compute done -> LDS reusable
    stage(t * BK);
    __syncthreads();            // compiler drains vmcnt(0) -> staged data ready

    // A fragments: read f32, trunc-Dekker split to hi/lo bf16 (6 VALU / pair)
    bf16x8 ah[4], al[4];
#pragma unroll
    for (int mi = 0; mi < 4; ++mi) {
      const unsigned char* ap = smem + (size_t)(wm + mi * 16 + frow) * 128;
      u32x4 q0 = *reinterpret_cast<const u32x4*>(ap + oA0);
      u32x4 q1 = *reinterpret_cast<const u32x4*>(ap + oA1);
      const uint32_t xs[8] = {q0[0], q0[1], q0[2], q0[3],
                              q1[0], q1[1], q1[2], q1[3]};
      u32x4 hv, lv;
#pragma unroll
      for (int p = 0; p < 4; ++p) {
        const uint32_t a = xs[2 * p], b = xs[2 * p + 1];
        hv[p] = __builtin_amdgcn_perm(b, a, 0x07060302u);  // [a.hi16 | b.hi16]
        const float la = __uint_as_float(a) - __uint_as_float(a & 0xffff0000u);
        const float lb = __uint_as_float(b) - __uint_as_float(b & 0xffff0000u);
        lv[p] = __builtin_amdgcn_perm(__float_as_uint(lb), __float_as_uint(la),
                                      0x07060302u);        // trunc-bf16 pack
      }
      ah[mi] = __builtin_bit_cast(bf16x8, hv);
      al[mi] = __builtin_bit_cast(bf16x8, lv);
    }

#pragma unroll
    for (int ni = 0; ni < 4; ++ni) {
      const unsigned char* bp = smem + 16384 + (size_t)(wn + ni * 16 + frow) * 64 + oB;
      bf16x8 bh = *reinterpret_cast<const bf16x8*>(bp);
      bf16x8 bl = *reinterpret_cast<const bf16x8*>(bp + 8192);
#pragma unroll
      for (int mi = 0; mi < 4; ++mi) {
        acc[mi][ni] = __builtin_amdgcn_mfma_f32_16x16x32_bf16(ah[mi], bh, acc[mi][ni], 0, 0, 0);
        acc[mi][ni] = __builtin_amdgcn_mfma_f32_16x16x32_bf16(al[mi], bh, acc[mi][ni], 0, 0, 0);
        acc[mi][ni] = __builtin_amdgcn_mfma_f32_16x16x32_bf16(ah[mi], bl, acc[mi][ni], 0, 0, 0);
      }
    }
  }

  // epilogue: C/D layout col = lane&15, row = (lane>>4)*4 + r  [m89-verified]
  const int colb = n0 + wn + (lane & 15);
  const int rowb = m0 + wm + ((lane >> 4) << 2);
#pragma unroll
  for (int ni = 0; ni < 4; ++ni) {
    const float bv = bias[colb + ni * 16];
#pragma unroll
    for (int mi = 0; mi < 4; ++mi) {
#pragma unroll
      for (int r = 0; r < 4; ++r) {
        C[(size_t)(rowb + mi * 16 + r) * NOUT + colb + ni * 16] = acc[mi][ni][r] + bv;
      }
    }
  }
}

// ---------------------------------------------------------------------------
// Fallback f32 GEMM (verified R1) — only if workspace is too small.
// ---------------------------------------------------------------------------
__global__ __launch_bounds__(256) void gemm_f32_64x64(
    const float* __restrict__ X, const float* __restrict__ W,
    const float* __restrict__ bias, float* __restrict__ C) {
  __shared__ float As[16][65];
  __shared__ float Bs[16][65];
  const int m0  = blockIdx.y * 64;
  const int n0  = blockIdx.x * 64;
  const int tid = threadIdx.x;
  const int tx  = tid & 15;
  const int ty  = tid >> 4;
  const int lr  = tid >> 2;
  const int lk  = (tid & 3) << 2;
  float acc[4][4] = {};
  const float* xa = X + (size_t)(m0 + lr) * KIN + lk;
  const float* wb = W + (size_t)(n0 + lr) * KIN + lk;
  for (int k0 = 0; k0 < KIN; k0 += 16) {
    float4 av = *reinterpret_cast<const float4*>(xa + k0);
    float4 bv = *reinterpret_cast<const float4*>(wb + k0);
    As[lk + 0][lr] = av.x; As[lk + 1][lr] = av.y;
    As[lk + 2][lr] = av.z; As[lk + 3][lr] = av.w;
    Bs[lk + 0][lr] = bv.x; Bs[lk + 1][lr] = bv.y;
    Bs[lk + 2][lr] = bv.z; Bs[lk + 3][lr] = bv.w;
    __syncthreads();
#pragma unroll
    for (int k = 0; k < 16; ++k) {
      float a[4], b[4];
#pragma unroll
      for (int i = 0; i < 4; ++i) a[i] = As[k][ty * 4 + i];
#pragma unroll
      for (int j = 0; j < 4; ++j) b[j] = Bs[k][tx * 4 + j];
#pragma unroll
      for (int i = 0; i < 4; ++i)
#pragma unroll
        for (int j = 0; j < 4; ++j) acc[i][j] += a[i] * b[j];
    }
    __syncthreads();
  }
  const int n = n0 + tx * 4;
  float4 bv = *reinterpret_cast<const float4*>(&bias[n]);
#pragma unroll
  for (int i = 0; i < 4; ++i) {
    const int m = m0 + ty * 4 + i;
    float4 r;
    r.x = acc[i][0] + bv.x; r.y = acc[i][1] + bv.y;
    r.z = acc[i][2] + bv.z; r.w = acc[i][3] + bv.w;
    *reinterpret_cast<float4*>(&C[(size_t)m * NOUT + n]) = r;
  }
}

// ---------------------------------------------------------------------------
// Chunked parallel scan (verified R3): vend (read-only) -> chunks -> fixup.
// ---------------------------------------------------------------------------
__global__ __launch_bounds__(512) void scan_vend(
    const float* __restrict__ C, const float* __restrict__ decay,
    float* __restrict__ vend) {
  const int b = blockIdx.x / NCHUNK;
  const int c = blockIdx.x % NCHUNK;
  const int o = threadIdx.x;
  const float d   = decay[o];
  const float omd = 1.0f - d;
  float v = 0.0f;
  size_t base = ((size_t)b * TT + (size_t)c * CHUNK) * NOUT + o;
#pragma unroll 4
  for (int k = 0; k < CHUNK; ++k) {
    v = d * v + omd * C[base + (size_t)k * NOUT];
  }
  vend[((size_t)b * NCHUNK + c) * NOUT + o] = v;
}

__global__ __launch_bounds__(512) void scan_chunks(
    const float* __restrict__ vend, const float* __restrict__ decay,
    float* __restrict__ vinit) {
  const int b = blockIdx.x;
  const int o = threadIdx.x;
  const float d = decay[o];
  float d2 = d * d, d4 = d2 * d2, d8 = d4 * d4, d16 = d8 * d8;
  const float dL = d16 * d16;   // d^CHUNK
  float V = 0.0f;
  for (int c = 0; c < NCHUNK; ++c) {
    const size_t idx = ((size_t)b * NCHUNK + c) * NOUT + o;
    vinit[idx] = V;
    V = dL * V + vend[idx];
  }
}

__global__ __launch_bounds__(512) void scan_fixup(
    float* __restrict__ C, float* __restrict__ states,
    const float* __restrict__ decay, const float* __restrict__ vinit) {
  const int b = blockIdx.x / NCHUNK;
  const int c = blockIdx.x % NCHUNK;
  const int o = threadIdx.x;
  const float d   = decay[o];
  const float omd = 1.0f - d;
  float v = vinit[((size_t)b * NCHUNK + c) * NOUT + o];  // seed = carry-in
  size_t obase = ((size_t)b * TT + (size_t)c * CHUNK) * NOUT + o;
  size_t sbase = ((size_t)b * (TT + 1) + (size_t)c * CHUNK + 1) * NOUT + o;
#pragma unroll 4
  for (int k = 0; k < CHUNK; ++k) {
    v = d * v + omd * C[obase + (size_t)k * NOUT];
    C[obase + (size_t)k * NOUT]      = v;
    states[sbase + (size_t)k * NOUT] = v;
  }
  if (c == 0) states[((size_t)b * (TT + 1)) * NOUT + o] = 0.0f;
}

__global__ __launch_bounds__(512) void scan_seq(
    float* __restrict__ C, float* __restrict__ states,
    const float* __restrict__ decay) {
  const int b = blockIdx.x;
  const int o = threadIdx.x;
  const float d   = decay[o];
  const float omd = 1.0f - d;
  float v = 0.0f;
  states[((size_t)b * (TT + 1)) * NOUT + o] = 0.0f;
  for (int t = 0; t < TT; ++t) {
    const size_t oi = ((size_t)b * TT + t) * NOUT + o;
    float x = C[oi];
    v = d * v + omd * x;
    C[oi] = v;
    states[((size_t)b * (TT + 1) + t + 1) * NOUT + o] = v;
  }
}

extern "C" void kernel_launch(void* const* d_in, const int* in_sizes, int n_in,
                              void* d_out, int out_size, void* d_ws, size_t ws_size,
                              hipStream_t stream) {
  const float* x     = (const float*)d_in[0];  // [B,T,IN]
  const float* w     = (const float*)d_in[1];  // [OUT,IN]
  const float* bias  = (const float*)d_in[2];  // [OUT]
  const float* decay = (const float*)d_in[3];  // [OUT]

  float* out    = (float*)d_out;                 // [B,T,OUT]
  float* states = out + (size_t)BB * TT * NOUT;  // [1,B,T+1,OUT]

  const size_t szW = (size_t)NOUT * KIN;                      // 0.52M elems
  const size_t scan_elems = (size_t)BB * NCHUNK * NOUT;
  const size_t need = 2 * szW * sizeof(unsigned short)
                    + 2 * scan_elems * sizeof(float);         // ~4 MB

  if (ws_size >= need) {
    unsigned short* Whi = (unsigned short*)d_ws;
    unsigned short* Wlo = Whi + szW;
    float* vend  = (float*)(Wlo + szW);
    float* vinit = vend + scan_elems;

    split_bf16_kernel<<<256, 256, 0, stream>>>(w, Whi, Wlo, (int)(szW / 8));
    gemm_fused<<<dim3((BB * TT) / BM, NOUT / BN), 256, 0, stream>>>(
        x, Whi, Wlo, bias, out);
    scan_vend  <<<BB * NCHUNK, NOUT, 0, stream>>>(out, decay, vend);
    scan_chunks<<<BB,          NOUT, 0, stream>>>(vend, decay, vinit);
    scan_fixup <<<BB * NCHUNK, NOUT, 0, stream>>>(out, states, decay, vinit);
  } else {
    gemm_f32_64x64<<<dim3(NOUT / 64, (BB * TT) / 64), 256, 0, stream>>>(x, w, bias, out);
    scan_seq<<<BB, NOUT, 0, stream>>>(out, states, decay);
  }
}

// Round 5
// 75.622 us; speedup vs baseline: 4.8293x; 1.2260x over previous
//
#include <hip/hip_runtime.h>
#include <hip/hip_bf16.h>
#include <cstddef>
#include <cstdint>

#define BB    8
#define TT    2048
#define KIN   1024
#define NOUT  512
#define CHUNK 32
#define NCHUNK (TT / CHUNK)   // 64

#define BM 128
#define BN 64
#define BK 32
#define NKSTEP (KIN / BK)     // 32

typedef __attribute__((ext_vector_type(4))) float          f32x4;
typedef __attribute__((ext_vector_type(4))) unsigned int   u32x4;
typedef _Float16 f16x8 __attribute__((ext_vector_type(8)));

// ---------------------------------------------------------------------------
// W f32 -> fp16 (RNE via scalar convert).  1 MB output, trivial pass.
// ---------------------------------------------------------------------------
__global__ __launch_bounds__(256) void conv_f16_kernel(
    const float* __restrict__ src, _Float16* __restrict__ dst, int n8) {
  int i = blockIdx.x * blockDim.x + threadIdx.x;
  const int stride = gridDim.x * blockDim.x;
  for (; i < n8; i += stride) {
    float4 x0 = reinterpret_cast<const float4*>(src)[2 * i];
    float4 x1 = reinterpret_cast<const float4*>(src)[2 * i + 1];
    f16x8 h;
    h[0] = (_Float16)x0.x; h[1] = (_Float16)x0.y;
    h[2] = (_Float16)x0.z; h[3] = (_Float16)x0.w;
    h[4] = (_Float16)x1.x; h[5] = (_Float16)x1.y;
    h[6] = (_Float16)x1.z; h[7] = (_Float16)x1.w;
    reinterpret_cast<f16x8*>(dst)[i] = h;
  }
}

#define G2L(gp, sp)                                                        \
  __builtin_amdgcn_global_load_lds(                                       \
      (const __attribute__((address_space(1))) void*)(gp),                \
      (__attribute__((address_space(3))) void*)(sp), 16, 0, 0)

// ---------------------------------------------------------------------------
// fp16 MFMA GEMM: A = f32 X staged via global_load_lds, converted to fp16
// in registers (v_cvt_pkrtz, RTZ); B = pre-converted fp16 W (RNE).
// Single MFMA term.  128x64 tile, BK=32, 20KB LDS single buffer, 2-barrier
// K-loop, XOR-swizzled LDS (pre-swizzled global source; verified R3/R4).
// grid = (128 m-strips, 8 n-tiles) = 1024 blocks = 4 blocks/CU co-resident;
// y-stride 128 == 0 mod 8 -> all 8 n-blocks of an m-strip on one XCD.
// ---------------------------------------------------------------------------
__global__ __launch_bounds__(256, 4) void gemm_f16(
    const float* __restrict__ X, const _Float16* __restrict__ Wh,
    const float* __restrict__ bias, float* __restrict__ C) {
  // A f32 16KB | B fp16 4KB = 20KB
  __shared__ __align__(16) unsigned char smem[16384 + 4096];

  const int tid  = threadIdx.x;
  const int wave = tid >> 6;
  const int lane = tid & 63;
  const int m0 = blockIdx.x * BM;
  const int n0 = blockIdx.y * BN;
  const int wm = (wave >> 1) * 64;   // 2x2 waves: 64x32 output each
  const int wn = (wave & 1) * 32;
  const int frow = lane & 15;

  // --- staging constants (inverse-swizzled global source, linear LDS dest) ---
  const int sgA  = (lane & 7) ^ (lane >> 3);        // A: 16B slot ^= row&7
  const int arow = wave * 8 + (lane >> 3);
  const int sgB  = (lane & 3) ^ ((lane >> 3) & 3);  // B: 16B slot ^= (row>>1)&3
  const int brow = wave * 16 + (lane >> 2);

  const float*    gA = X  + (size_t)(m0 + arow) * KIN + sgA * 4;
  const _Float16* gB = Wh + (size_t)(n0 + brow) * KIN + sgB * 8;
  const int ldsw = wave * 1024;   // bytes: wave's lane-linear slice per issue

  // --- fragment-read constants (swizzled byte offsets, constant per lane) ---
  const int s0  = (lane >> 4) * 2;
  const int oA0 = ((s0)     ^ (lane & 7)) << 4;
  const int oA1 = ((s0 + 1) ^ (lane & 7)) << 4;
  const int oB  = ((lane >> 4) ^ ((lane >> 1) & 3)) << 4;

  f32x4 acc[4][2] = {};

  for (int t = 0; t < NKSTEP; ++t) {
    const int k0 = t * BK;
    __syncthreads();            // previous compute done -> LDS reusable
#pragma unroll
    for (int i = 0; i < 4; ++i)
      G2L(gA + (size_t)i * 32 * KIN + k0, smem + i * 4096 + ldsw);
    G2L(gB + k0, smem + 16384 + ldsw);
    __syncthreads();            // vmcnt(0) drain -> staged data ready

    // A fragments: read f32, convert to fp16 via packed RTZ (1 op / pair)
    f16x8 af[4];
#pragma unroll
    for (int mi = 0; mi < 4; ++mi) {
      const unsigned char* ap = smem + (size_t)(wm + mi * 16 + frow) * 128;
      f32x4 q0 = *reinterpret_cast<const f32x4*>(ap + oA0);
      f32x4 q1 = *reinterpret_cast<const f32x4*>(ap + oA1);
      u32x4 hv;
      hv[0] = __builtin_bit_cast(unsigned int, __builtin_amdgcn_cvt_pkrtz(q0[0], q0[1]));
      hv[1] = __builtin_bit_cast(unsigned int, __builtin_amdgcn_cvt_pkrtz(q0[2], q0[3]));
      hv[2] = __builtin_bit_cast(unsigned int, __builtin_amdgcn_cvt_pkrtz(q1[0], q1[1]));
      hv[3] = __builtin_bit_cast(unsigned int, __builtin_amdgcn_cvt_pkrtz(q1[2], q1[3]));
      af[mi] = __builtin_bit_cast(f16x8, hv);
    }

#pragma unroll
    for (int ni = 0; ni < 2; ++ni) {
      const unsigned char* bp = smem + 16384 + (size_t)(wn + ni * 16 + frow) * 64 + oB;
      f16x8 bf = *reinterpret_cast<const f16x8*>(bp);
#pragma unroll
      for (int mi = 0; mi < 4; ++mi)
        acc[mi][ni] = __builtin_amdgcn_mfma_f32_16x16x32_f16(af[mi], bf, acc[mi][ni], 0, 0, 0);
    }
  }

  // epilogue: C/D layout col = lane&15, row = (lane>>4)*4 + r  [m89-verified]
  const int colb = n0 + wn + (lane & 15);
  const int rowb = m0 + wm + ((lane >> 4) << 2);
#pragma unroll
  for (int ni = 0; ni < 2; ++ni) {
    const float bv = bias[colb + ni * 16];
#pragma unroll
    for (int mi = 0; mi < 4; ++mi) {
#pragma unroll
      for (int r = 0; r < 4; ++r) {
        C[(size_t)(rowb + mi * 16 + r) * NOUT + colb + ni * 16] = acc[mi][ni][r] + bv;
      }
    }
  }
}

// ---------------------------------------------------------------------------
// Fallback f32 GEMM (verified R1) — only if workspace is too small.
// ---------------------------------------------------------------------------
__global__ __launch_bounds__(256) void gemm_f32_64x64(
    const float* __restrict__ X, const float* __restrict__ W,
    const float* __restrict__ bias, float* __restrict__ C) {
  __shared__ float As[16][65];
  __shared__ float Bs[16][65];
  const int m0  = blockIdx.y * 64;
  const int n0  = blockIdx.x * 64;
  const int tid = threadIdx.x;
  const int tx  = tid & 15;
  const int ty  = tid >> 4;
  const int lr  = tid >> 2;
  const int lk  = (tid & 3) << 2;
  float acc[4][4] = {};
  const float* xa = X + (size_t)(m0 + lr) * KIN + lk;
  const float* wb = W + (size_t)(n0 + lr) * KIN + lk;
  for (int k0 = 0; k0 < KIN; k0 += 16) {
    float4 av = *reinterpret_cast<const float4*>(xa + k0);
    float4 bv = *reinterpret_cast<const float4*>(wb + k0);
    As[lk + 0][lr] = av.x; As[lk + 1][lr] = av.y;
    As[lk + 2][lr] = av.z; As[lk + 3][lr] = av.w;
    Bs[lk + 0][lr] = bv.x; Bs[lk + 1][lr] = bv.y;
    Bs[lk + 2][lr] = bv.z; Bs[lk + 3][lr] = bv.w;
    __syncthreads();
#pragma unroll
    for (int k = 0; k < 16; ++k) {
      float a[4], b[4];
#pragma unroll
      for (int i = 0; i < 4; ++i) a[i] = As[k][ty * 4 + i];
#pragma unroll
      for (int j = 0; j < 4; ++j) b[j] = Bs[k][tx * 4 + j];
#pragma unroll
      for (int i = 0; i < 4; ++i)
#pragma unroll
        for (int j = 0; j < 4; ++j) acc[i][j] += a[i] * b[j];
    }
    __syncthreads();
  }
  const int n = n0 + tx * 4;
  float4 bv = *reinterpret_cast<const float4*>(&bias[n]);
#pragma unroll
  for (int i = 0; i < 4; ++i) {
    const int m = m0 + ty * 4 + i;
    float4 r;
    r.x = acc[i][0] + bv.x; r.y = acc[i][1] + bv.y;
    r.z = acc[i][2] + bv.z; r.w = acc[i][3] + bv.w;
    *reinterpret_cast<float4*>(&C[(size_t)m * NOUT + n]) = r;
  }
}

// ---------------------------------------------------------------------------
// Chunked parallel scan (verified R3/R4): vend (read-only) -> chunks -> fixup.
// ---------------------------------------------------------------------------
__global__ __launch_bounds__(512) void scan_vend(
    const float* __restrict__ C, const float* __restrict__ decay,
    float* __restrict__ vend) {
  const int b = blockIdx.x / NCHUNK;
  const int c = blockIdx.x % NCHUNK;
  const int o = threadIdx.x;
  const float d   = decay[o];
  const float omd = 1.0f - d;
  float v = 0.0f;
  size_t base = ((size_t)b * TT + (size_t)c * CHUNK) * NOUT + o;
#pragma unroll 4
  for (int k = 0; k < CHUNK; ++k) {
    v = d * v + omd * C[base + (size_t)k * NOUT];
  }
  vend[((size_t)b * NCHUNK + c) * NOUT + o] = v;
}

__global__ __launch_bounds__(512) void scan_chunks(
    const float* __restrict__ vend, const float* __restrict__ decay,
    float* __restrict__ vinit) {
  const int b = blockIdx.x;
  const int o = threadIdx.x;
  const float d = decay[o];
  float d2 = d * d, d4 = d2 * d2, d8 = d4 * d4, d16 = d8 * d8;
  const float dL = d16 * d16;   // d^CHUNK
  float V = 0.0f;
  for (int c = 0; c < NCHUNK; ++c) {
    const size_t idx = ((size_t)b * NCHUNK + c) * NOUT + o;
    vinit[idx] = V;
    V = dL * V + vend[idx];
  }
}

__global__ __launch_bounds__(512) void scan_fixup(
    float* __restrict__ C, float* __restrict__ states,
    const float* __restrict__ decay, const float* __restrict__ vinit) {
  const int b = blockIdx.x / NCHUNK;
  const int c = blockIdx.x % NCHUNK;
  const int o = threadIdx.x;
  const float d   = decay[o];
  const float omd = 1.0f - d;
  float v = vinit[((size_t)b * NCHUNK + c) * NOUT + o];  // seed = carry-in
  size_t obase = ((size_t)b * TT + (size_t)c * CHUNK) * NOUT + o;
  size_t sbase = ((size_t)b * (TT + 1) + (size_t)c * CHUNK + 1) * NOUT + o;
#pragma unroll 4
  for (int k = 0; k < CHUNK; ++k) {
    v = d * v + omd * C[obase + (size_t)k * NOUT];
    C[obase + (size_t)k * NOUT]      = v;
    states[sbase + (size_t)k * NOUT] = v;
  }
  if (c == 0) states[((size_t)b * (TT + 1)) * NOUT + o] = 0.0f;
}

__global__ __launch_bounds__(512) void scan_seq(
    float* __restrict__ C, float* __restrict__ states,
    const float* __restrict__ decay) {
  const int b = blockIdx.x;
  const int o = threadIdx.x;
  const float d   = decay[o];
  const float omd = 1.0f - d;
  float v = 0.0f;
  states[((size_t)b * (TT + 1)) * NOUT + o] = 0.0f;
  for (int t = 0; t < TT; ++t) {
    const size_t oi = ((size_t)b * TT + t) * NOUT + o;
    float x = C[oi];
    v = d * v + omd * x;
    C[oi] = v;
    states[((size_t)b * (TT + 1) + t + 1) * NOUT + o] = v;
  }
}

extern "C" void kernel_launch(void* const* d_in, const int* in_sizes, int n_in,
                              void* d_out, int out_size, void* d_ws, size_t ws_size,
                              hipStream_t stream) {
  const float* x     = (const float*)d_in[0];  // [B,T,IN]
  const float* w     = (const float*)d_in[1];  // [OUT,IN]
  const float* bias  = (const float*)d_in[2];  // [OUT]
  const float* decay = (const float*)d_in[3];  // [OUT]

  float* out    = (float*)d_out;                 // [B,T,OUT]
  float* states = out + (size_t)BB * TT * NOUT;  // [1,B,T+1,OUT]

  const size_t szW = (size_t)NOUT * KIN;                      // 0.52M elems
  const size_t scan_elems = (size_t)BB * NCHUNK * NOUT;
  const size_t need = szW * sizeof(_Float16)
                    + 2 * scan_elems * sizeof(float);         // ~3 MB

  if (ws_size >= need) {
    _Float16* Wh = (_Float16*)d_ws;
    float* vend  = (float*)(Wh + szW);
    float* vinit = vend + scan_elems;

    conv_f16_kernel<<<256, 256, 0, stream>>>(w, Wh, (int)(szW / 8));
    gemm_f16<<<dim3((BB * TT) / BM, NOUT / BN), 256, 0, stream>>>(
        x, Wh, bias, out);
    scan_vend  <<<BB * NCHUNK, NOUT, 0, stream>>>(out, decay, vend);
    scan_chunks<<<BB,          NOUT, 0, stream>>>(vend, decay, vinit);
    scan_fixup <<<BB * NCHUNK, NOUT, 0, stream>>>(out, states, decay, vinit);
  } else {
    gemm_f32_64x64<<<dim3(NOUT / 64, (BB * TT) / 64), 256, 0, stream>>>(x, w, bias, out);
    scan_seq<<<BB, NOUT, 0, stream>>>(out, states, decay);
  }
}